// Round 14
// baseline (197.801 us; speedup 1.0000x reference)
//
#include <hip/hip_runtime.h>

// ---------------------------------------------------------------------------
// Pipeline (8 launches):
//   k_prepw:     weight bf16 packs + deg zero
//   k_hist:      deg histogram + per-edge rank (1 int atomic/edge)
//   k_scan_partial / k_scan_final: off = scan(deg); sd/rdeg/nstart; zero
//                boundary rows (scan_final self-computes block offsets)
//   k_scatcvt:   ea (streaming, 4 edges/thread) -> bf16 -> easorted[pos]
//                (64B full-line random write, L2-buffered) + colsort (u16)
//   k_agg:       streaming easorted -> MFMA edge GEMV -> LDS -> segmented
//                sums; INTERIOR nodes written in final form (out[:,64:96] +
//                eagg_bf); boundary/empty via fp32 atomics into eagg
//   k_nodecvt:   node blocks: MFMA node GEMM -> out[:,0:64],[128:224];
//                cvt blocks: finalize ONLY boundary/empty nodes
//   k_mmagg:     out[:,96:128] = dinv * gather-sum(eagg_bf[colsort])
// NOTE (r11 lesson): NO nontemporal stores on scattered addresses — they
// bypass L2 write-coalescing and regress 2-5x.
// Math:
//   out[:,  0: 64] = relu(x @ W_ego.T + b_ego)
//   out[:, 64: 96] = eagg[i]  = sum_{e:row=i} relu(ea[e] @ W_edge.T + b_edge)
//   out[:, 96:128] = dinv[i] * sum_{e:row=i} eagg[col[e]]
//   out[:,128:224] = relu( sd * (W_peer @ [x | sea/deg] + b_peer) )
// MFMA fragment maps: A/B k-order cancels (same map both sides); C/D layout
// (HW-verified): col = lane&15, row = (lane>>4)*4 + reg.
// colsort is u16 — requires N <= 65535 (here N = 50000).
// ---------------------------------------------------------------------------

typedef float f32x4 __attribute__((ext_vector_type(4)));
typedef short bf16x8 __attribute__((ext_vector_type(8)));
typedef unsigned short u16x8 __attribute__((ext_vector_type(8)));

#define BP 256   // CSR positions per k_agg block (512 threads, 2 edges/thread)

__device__ __forceinline__ unsigned short f2bf(float f) {
    unsigned u = __float_as_uint(f);
    u += 0x7fffu + ((u >> 16) & 1u);      // RNE
    return (unsigned short)(u >> 16);
}
__device__ __forceinline__ float bf2f(unsigned short u) {
    return __uint_as_float((unsigned)u << 16);
}
__device__ __forceinline__ u16x8 pk8u(float4 lo, float4 hi) {
    u16x8 r;
    r[0]=f2bf(lo.x); r[1]=f2bf(lo.y); r[2]=f2bf(lo.z); r[3]=f2bf(lo.w);
    r[4]=f2bf(hi.x); r[5]=f2bf(hi.y); r[6]=f2bf(hi.z); r[7]=f2bf(hi.w);
    return r;
}
__device__ __forceinline__ bf16x8 mk_frag(ushort4 lo, ushort4 hi) {
    bf16x8 b;
    b[0]=(short)lo.x; b[1]=(short)lo.y; b[2]=(short)lo.z; b[3]=(short)lo.w;
    b[4]=(short)hi.x; b[5]=(short)hi.y; b[6]=(short)hi.z; b[7]=(short)hi.w;
    return b;
}
__device__ __forceinline__ bf16x8 ld_bfrag(const unsigned short* bp) {
    return mk_frag(*reinterpret_cast<const ushort4*>(bp),
                   *reinterpret_cast<const ushort4*>(bp + 16));
}

// weight packs + deg zero (merged)
__global__ __launch_bounds__(256) void k_prepw(const float* __restrict__ W_ego,
                                               const float* __restrict__ W_peer,
                                               const float* __restrict__ W_edge,
                                               unsigned short* __restrict__ Bt,
                                               unsigned short* __restrict__ Bte,
                                               int* __restrict__ deg, int N) {
    int idx = blockIdx.x * blockDim.x + threadIdx.x;
    if (idx < 160 * 160) {
        int n = idx / 160, k = idx % 160;
        float v;
        if (n < 64) v = (k < 128) ? W_ego[n * 128 + k] : 0.f;
        else        v = W_peer[(n - 64) * 160 + k];
        Bt[idx] = f2bf(v);
    } else if (idx < 160 * 160 + 32 * 32) {
        int j = idx - 160 * 160;
        Bte[j] = f2bf(W_edge[j]);
    }
    if (idx < N) deg[idx] = 0;
}

// histogram + per-edge rank within its node
__global__ __launch_bounds__(256) void k_hist(const int* __restrict__ row,
                                              int* __restrict__ deg,
                                              int* __restrict__ rank, int E) {
    int e = blockIdx.x * blockDim.x + threadIdx.x;
    if (e < E) rank[e] = atomicAdd(&deg[row[e]], 1);
}

__global__ __launch_bounds__(256) void k_scan_partial(const int* __restrict__ deg,
                                                      int* __restrict__ bsum, int N) {
    __shared__ int sh[256];
    int base = blockIdx.x * 1024 + threadIdx.x * 4;
    int s = 0;
#pragma unroll
    for (int q = 0; q < 4; ++q) { int i = base + q; if (i < N) s += deg[i]; }
    sh[threadIdx.x] = s;
    __syncthreads();
    for (int off = 128; off > 0; off >>= 1) {
        if (threadIdx.x < off) sh[threadIdx.x] += sh[threadIdx.x + off];
        __syncthreads();
    }
    if (threadIdx.x == 0) bsum[blockIdx.x] = sh[0];
}

// scan-final + per-node prep. Each block derives its own prefix from bsum
// (NB = gridDim.x <= 64), so no separate mid kernel.
__global__ __launch_bounds__(256) void k_scan_final(
    const int* __restrict__ deg, const int* __restrict__ bsum,
    int* __restrict__ off,
    float* __restrict__ sd, float* __restrict__ rdeg, int* __restrict__ nstart,
    float* __restrict__ eagg, float* __restrict__ sea, int N)
{
    __shared__ int sh[256];
    __shared__ int s_boff;
    int t = threadIdx.x;
    int NB = gridDim.x;

    if (t < 64) {                         // one wave computes prefix + total
        int v = (t < NB) ? bsum[t] : 0;
        int p = (t < (int)blockIdx.x) ? v : 0;
#pragma unroll
        for (int m = 1; m < 64; m <<= 1) {
            p += __shfl_xor(p, m);
            v += __shfl_xor(v, m);
        }
        if (t == 0) {
            s_boff = p;
            if (blockIdx.x == 0) off[N] = v;   // total == E
        }
    }
    __syncthreads();

    int base = blockIdx.x * 1024 + t * 4;
    int v[4];
#pragma unroll
    for (int q = 0; q < 4; ++q) v[q] = (base + q < N) ? deg[base + q] : 0;
    int ts = v[0] + v[1] + v[2] + v[3];
    sh[t] = ts;
    __syncthreads();
    int incl = ts;
    for (int d = 1; d < 256; d <<= 1) {
        int val = (t >= d) ? sh[t - d] : 0;
        __syncthreads();
        incl += val;
        sh[t] = incl;
        __syncthreads();
    }
    int running = s_boff + incl - ts;
#pragma unroll
    for (int q = 0; q < 4; ++q) {
        int i = base + q;
        if (i < N) {
            int s = running, e = running + v[q];
            off[i] = s;
            int dg = v[q];
            sd[i]   = dg > 0 ? sqrtf((float)dg) : 0.f;
            rdeg[i] = dg > 0 ? 1.f / (float)dg : 0.f;
            for (int b = (s + BP - 1) / BP; b * BP < e; ++b) nstart[b] = i;
            bool zneed = (dg == 0) || ((s / BP) != ((e - 1) / BP));
            if (zneed) {
                float4 z = {0.f, 0.f, 0.f, 0.f};
                float4* pe = reinterpret_cast<float4*>(eagg + (size_t)i * 32);
                float4* ps = reinterpret_cast<float4*>(sea  + (size_t)i * 32);
#pragma unroll
                for (int q2 = 0; q2 < 8; ++q2) { pe[q2] = z; ps[q2] = z; }
            }
            running = e;
        }
    }
}

// streaming ea read -> bf16 -> full-line (64B) random write; 4 edges/thread
// with int4 index loads -> 4 independent lookup->store chains.
__global__ __launch_bounds__(256) void k_scatcvt(
    const float* __restrict__ ea, const int* __restrict__ row,
    const int* __restrict__ col, const int* __restrict__ off,
    const int* __restrict__ rank,
    unsigned short* __restrict__ easorted,
    unsigned short* __restrict__ colsort, int E)
{
    int base = (blockIdx.x * 256 + threadIdx.x) * 4;
    if (base >= E) return;
    if (base + 3 < E) {
        int4 r4 = *reinterpret_cast<const int4*>(row + base);
        int4 k4 = *reinterpret_cast<const int4*>(rank + base);
        int4 c4 = *reinterpret_cast<const int4*>(col + base);
        int pos0 = off[r4.x] + k4.x;
        int pos1 = off[r4.y] + k4.y;
        int pos2 = off[r4.z] + k4.z;
        int pos3 = off[r4.w] + k4.w;
        int posv[4] = {pos0, pos1, pos2, pos3};
        int colv[4] = {c4.x, c4.y, c4.z, c4.w};
#pragma unroll
        for (int j = 0; j < 4; ++j) {
            const float4* src = reinterpret_cast<const float4*>(ea + (size_t)(base + j) * 32);
            u16x8* dst = reinterpret_cast<u16x8*>(easorted + (size_t)posv[j] * 32);
#pragma unroll
            for (int q = 0; q < 4; ++q)
                dst[q] = pk8u(src[2 * q], src[2 * q + 1]);
            colsort[posv[j]] = (unsigned short)colv[j];
        }
    } else {
        for (int e = base; e < E; ++e) {
            int pos = off[row[e]] + rank[e];
            const float4* src = reinterpret_cast<const float4*>(ea + (size_t)e * 32);
            u16x8* dst = reinterpret_cast<u16x8*>(easorted + (size_t)pos * 32);
#pragma unroll
            for (int q = 0; q < 4; ++q)
                dst[q] = pk8u(src[2 * q], src[2 * q + 1]);
            colsort[pos] = (unsigned short)col[e];
        }
    }
}

// Streaming sorted records -> MFMA edge GEMV -> bf16 LDS -> segmented sum.
// Interior nodes finalized here (out[:,64:96] + eagg_bf); boundary/empty via
// fp32 atomics into eagg (zeroed by scan_final), finalized by k_nodecvt.
__global__ __launch_bounds__(512) void k_agg(
    const unsigned short* __restrict__ easorted,
    const int* __restrict__ off, const int* __restrict__ nstart,
    const unsigned short* __restrict__ Bte, const float* __restrict__ b_edge,
    float* __restrict__ eagg, float* __restrict__ sea,
    unsigned short* __restrict__ eagg_bf, float* __restrict__ out, int N, int E)
{
    __shared__ unsigned short hs [BP][36];   // relu(h_e), bf16
    __shared__ unsigned short asr[BP][36];   // raw ea,    bf16
    const int tid  = threadIdx.x;
    const int w    = tid >> 6;
    const int lane = tid & 63;
    const int n16  = lane & 15;
    const int h    = lane >> 4;
    const int P    = blockIdx.x * BP;

    // ---- phase 1: streaming record read + MFMA GEMV (2 edges/thread) ----
    {
        const int tA = w * 32 + n16;                 // block-local CSR pos (tile 0)
        const int p0 = min(P + tA,      E - 1);
        const int p1 = min(P + tA + 16, E - 1);
        const unsigned short* r0 = easorted + (size_t)p0 * 32 + h * 4;
        const unsigned short* r1 = easorted + (size_t)p1 * 32 + h * 4;
        ushort4 lo0 = *reinterpret_cast<const ushort4*>(r0);
        ushort4 hi0 = *reinterpret_cast<const ushort4*>(r0 + 16);
        ushort4 lo1 = *reinterpret_cast<const ushort4*>(r1);
        ushort4 hi1 = *reinterpret_cast<const ushort4*>(r1 + 16);

        *reinterpret_cast<ushort4*>(&asr[tA][h * 4])           = lo0;
        *reinterpret_cast<ushort4*>(&asr[tA][16 + h * 4])      = hi0;
        *reinterpret_cast<ushort4*>(&asr[tA + 16][h * 4])      = lo1;
        *reinterpret_cast<ushort4*>(&asr[tA + 16][16 + h * 4]) = hi1;

        bf16x8 a0 = mk_frag(lo0, hi0);
        bf16x8 a1 = mk_frag(lo1, hi1);
        bf16x8 b0 = ld_bfrag(Bte + (size_t)n16 * 32 + h * 4);
        bf16x8 b1 = ld_bfrag(Bte + (size_t)(16 + n16) * 32 + h * 4);
        f32x4 d00 = {0.f,0.f,0.f,0.f}, d01 = {0.f,0.f,0.f,0.f};
        f32x4 d10 = {0.f,0.f,0.f,0.f}, d11 = {0.f,0.f,0.f,0.f};
        d00 = __builtin_amdgcn_mfma_f32_16x16x32_bf16(a0, b0, d00, 0, 0, 0);
        d01 = __builtin_amdgcn_mfma_f32_16x16x32_bf16(a0, b1, d01, 0, 0, 0);
        d10 = __builtin_amdgcn_mfma_f32_16x16x32_bf16(a1, b0, d10, 0, 0, 0);
        d11 = __builtin_amdgcn_mfma_f32_16x16x32_bf16(a1, b1, d11, 0, 0, 0);

        const int tr0 = w * 32 + h * 4;              // D row base = edge
        float be0 = b_edge[n16], be1 = b_edge[16 + n16];
#pragma unroll
        for (int r = 0; r < 4; ++r) {
            hs[tr0 + r][n16]           = f2bf(fmaxf(d00[r] + be0, 0.f));
            hs[tr0 + r][16 + n16]      = f2bf(fmaxf(d01[r] + be1, 0.f));
            hs[tr0 + 16 + r][n16]      = f2bf(fmaxf(d10[r] + be0, 0.f));
            hs[tr0 + 16 + r][16 + n16] = f2bf(fmaxf(d11[r] + be1, 0.f));
        }
    }
    __syncthreads();

    // ---- phase 2: segmented sums from LDS (nstart precomputed) ----
    const int c = lane & 7, sub = lane >> 3;
    const int node0 = nstart[blockIdx.x];

    for (int n = node0 + w; n < N; n += 8) {
        int s0 = off[n];
        if (s0 >= P + BP) break;                     // off monotone -> done
        int e0 = off[n + 1];
        int s = max(s0, P) - P, eEnd = min(e0, P + BP) - P;
        float4 hv = {0.f,0.f,0.f,0.f}, av = {0.f,0.f,0.f,0.f};
        for (int t = s + sub; t < eEnd; t += 8) {
            ushort4 uh = *reinterpret_cast<const ushort4*>(&hs [t][c * 4]);
            ushort4 ua = *reinterpret_cast<const ushort4*>(&asr[t][c * 4]);
            hv.x += bf2f(uh.x); hv.y += bf2f(uh.y); hv.z += bf2f(uh.z); hv.w += bf2f(uh.w);
            av.x += bf2f(ua.x); av.y += bf2f(ua.y); av.z += bf2f(ua.z); av.w += bf2f(ua.w);
        }
#pragma unroll
        for (int m = 8; m < 64; m <<= 1) {
            hv.x += __shfl_xor(hv.x, m); hv.y += __shfl_xor(hv.y, m);
            hv.z += __shfl_xor(hv.z, m); hv.w += __shfl_xor(hv.w, m);
            av.x += __shfl_xor(av.x, m); av.y += __shfl_xor(av.y, m);
            av.z += __shfl_xor(av.z, m); av.w += __shfl_xor(av.w, m);
        }
        if (lane < 8) {
            bool interior = (s0 >= P) && (e0 <= P + BP);
            float* ps = sea + (size_t)n * 32 + c * 4;
            if (interior) {
                // finalize directly: out[:,64:96] fp32 + eagg_bf bf16 + sea
                *reinterpret_cast<float4*>(out + (size_t)n * 224 + 64 + c * 4) = hv;
                ushort4 ub = {f2bf(hv.x), f2bf(hv.y), f2bf(hv.z), f2bf(hv.w)};
                *reinterpret_cast<ushort4*>(eagg_bf + (size_t)n * 32 + c * 4) = ub;
                *reinterpret_cast<float4*>(ps) = av;
            } else {
                float* pe = eagg + (size_t)n * 32 + c * 4;
                atomicAdd(pe+0,hv.x); atomicAdd(pe+1,hv.y);
                atomicAdd(pe+2,hv.z); atomicAdd(pe+3,hv.w);
                atomicAdd(ps+0,av.x); atomicAdd(ps+1,av.y);
                atomicAdd(ps+2,av.z); atomicAdd(ps+3,av.w);
            }
        }
    }
}

// Merged: blocks [0, node_grid) = MFMA node GEMM; blocks after = finalize
// boundary/empty nodes only (eagg fp32 -> eagg_bf + out[:,64:96]).
__global__ __launch_bounds__(256) void k_nodecvt(
    const float* __restrict__ x, const float* __restrict__ sea,
    const float* __restrict__ sd, const float* __restrict__ rdeg,
    const unsigned short* __restrict__ Bt,
    const float* __restrict__ b_ego, const float* __restrict__ b_peer,
    const float* __restrict__ eagg, unsigned short* __restrict__ eagg_bf,
    const int* __restrict__ off,
    float* __restrict__ out, int N, int node_grid)
{
    if ((int)blockIdx.x >= node_grid) {
        // ---- finalize boundary/empty nodes ----
        int idx = (blockIdx.x - node_grid) * 256 + threadIdx.x;
        if (idx >= N * 8) return;
        int node = idx >> 3, c = idx & 7;
        int s = off[node], e = off[node + 1];
        int dg = e - s;
        bool zneed = (dg == 0) || ((s / BP) != ((e - 1) / BP));
        if (!zneed) return;
        float4 v = reinterpret_cast<const float4*>(eagg + (size_t)node * 32)[c];
        ushort4 u = {f2bf(v.x), f2bf(v.y), f2bf(v.z), f2bf(v.w)};
        *reinterpret_cast<ushort4*>(eagg_bf + (size_t)node * 32 + c * 4) = u;
        reinterpret_cast<float4*>(out + (size_t)node * 224 + 64)[c] = v;
        return;
    }
    // ---- node GEMM part: block = 4 waves, wave = 16 nodes x 160 outputs ----
    const int lane = threadIdx.x & 63;
    const int wv   = threadIdx.x >> 6;
    const int wm   = blockIdx.x * 64 + wv * 16;
    const int n16  = lane & 15;
    const int h    = lane >> 4;

    const int m_l = min(wm + n16, N - 1);

    f32x4 acc[10];
#pragma unroll
    for (int f = 0; f < 10; ++f) acc[f] = (f32x4){0.f,0.f,0.f,0.f};

#pragma unroll
    for (int kc = 0; kc < 5; ++kc) {
        bf16x8 bfr[10];
#pragma unroll
        for (int f = 0; f < 10; ++f)
            bfr[f] = ld_bfrag(Bt + (size_t)(f * 16 + n16) * 160 + kc * 32 + h * 4);
        float4 lo, hi;
        if (kc < 4) {
            const float* ap = x + (size_t)m_l * 128 + kc * 32 + h * 4;
            lo = *reinterpret_cast<const float4*>(ap);
            hi = *reinterpret_cast<const float4*>(ap + 16);
        } else {
            float r = rdeg[m_l];
            const float* ap = sea + (size_t)m_l * 32 + h * 4;
            lo = *reinterpret_cast<const float4*>(ap);
            hi = *reinterpret_cast<const float4*>(ap + 16);
            lo.x*=r; lo.y*=r; lo.z*=r; lo.w*=r;
            hi.x*=r; hi.y*=r; hi.z*=r; hi.w*=r;
        }
        u16x8 au = pk8u(lo, hi);
        bf16x8 a;
#pragma unroll
        for (int q = 0; q < 8; ++q) a[q] = (short)au[q];
#pragma unroll
        for (int f = 0; f < 10; ++f)
            acc[f] = __builtin_amdgcn_mfma_f32_16x16x32_bf16(a, bfr[f], acc[f], 0, 0, 0);
    }

    const int r4 = h * 4;
    float sdv[4];
#pragma unroll
    for (int r = 0; r < 4; ++r) {
        int node = wm + r4 + r;
        sdv[r] = (node < N) ? sd[node] : 0.f;
    }
#pragma unroll
    for (int f = 0; f < 10; ++f) {
        int c = f * 16 + n16;
        float be = (c < 64)  ? b_ego[c] : 0.f;
        float bp = (c >= 64) ? b_peer[c - 64] : 0.f;
#pragma unroll
        for (int r = 0; r < 4; ++r) {
            int node = wm + r4 + r;
            if (node >= N) continue;
            float v = acc[f][r];
            if (c < 64)
                out[(size_t)node * 224 + c] = fmaxf(v + be, 0.f);
            else
                out[(size_t)node * 224 + 64 + c] = fmaxf(sdv[r] * (v + bp), 0.f);
        }
    }
}

// out[:,96:128] = dinv * gather-sum(eagg_bf[colsort])  (64B L2-hit gathers)
__global__ __launch_bounds__(256) void k_mmagg(
    const unsigned short* __restrict__ colsort, const int* __restrict__ off,
    const unsigned short* __restrict__ eagg_bf, float* __restrict__ out, int N)
{
    int wid  = (blockIdx.x * blockDim.x + threadIdx.x) >> 6;
    int lane = threadIdx.x & 63;
    if (wid >= N) return;
    int s = off[wid], e = off[wid + 1];
    int c   = lane & 7;
    int sub = lane >> 3;
    float4 acc = {0.f, 0.f, 0.f, 0.f};
    float4 acc2 = {0.f, 0.f, 0.f, 0.f};
    for (int t0 = s; t0 < e; t0 += 16) {
        int t1 = t0 + sub, t2 = t0 + 8 + sub;
        if (t1 < e) {
            ushort4 u = *reinterpret_cast<const ushort4*>(
                eagg_bf + (size_t)colsort[t1] * 32 + c * 4);
            acc.x += bf2f(u.x); acc.y += bf2f(u.y);
            acc.z += bf2f(u.z); acc.w += bf2f(u.w);
        }
        if (t2 < e) {
            ushort4 u = *reinterpret_cast<const ushort4*>(
                eagg_bf + (size_t)colsort[t2] * 32 + c * 4);
            acc2.x += bf2f(u.x); acc2.y += bf2f(u.y);
            acc2.z += bf2f(u.z); acc2.w += bf2f(u.w);
        }
    }
    acc.x += acc2.x; acc.y += acc2.y; acc.z += acc2.z; acc.w += acc2.w;
#pragma unroll
    for (int m = 8; m < 64; m <<= 1) {
        acc.x += __shfl_xor(acc.x, m);
        acc.y += __shfl_xor(acc.y, m);
        acc.z += __shfl_xor(acc.z, m);
        acc.w += __shfl_xor(acc.w, m);
    }
    int dg = e - s;
    float dinv = dg > 0 ? rsqrtf((float)dg) : 0.f;
    if (lane < 8) {
        float4 o4 = {acc.x * dinv, acc.y * dinv, acc.z * dinv, acc.w * dinv};
        reinterpret_cast<float4*>(out + (size_t)wid * 224 + 96)[c] = o4;
    }
}

extern "C" void kernel_launch(void* const* d_in, const int* in_sizes, int n_in,
                              void* d_out, int out_size, void* d_ws, size_t ws_size,
                              hipStream_t stream)
{
    const float* x      = (const float*)d_in[0];
    const float* ea     = (const float*)d_in[1];
    const float* W_peer = (const float*)d_in[2];
    const float* b_peer = (const float*)d_in[3];
    const float* W_ego  = (const float*)d_in[4];
    const float* b_ego  = (const float*)d_in[5];
    const float* W_edge = (const float*)d_in[6];
    const float* b_edge = (const float*)d_in[7];
    const int*   ei     = (const int*)d_in[8];

    const int N = in_sizes[0] / 128;
    const int E = in_sizes[8] / 2;
    const int* col = ei;
    const int* row = ei + E;
    const int nblocks = (E + BP - 1) / BP;

    // 16B-aligned workspace carve-out
    char* wp = (char*)d_ws;
    auto carve = [&](size_t bytes) { char* r = wp; wp += (bytes + 15) & ~(size_t)15; return r; };
    int*            rank     = (int*)carve((size_t)E * 4);
    unsigned short* easorted = (unsigned short*)carve((size_t)E * 64);
    unsigned short* colsort  = (unsigned short*)carve((size_t)E * 2);
    int*            deg_i    = (int*)carve((size_t)N * 4);
    float*          eagg     = (float*)carve((size_t)N * 128);
    float*          sea      = (float*)carve((size_t)N * 128);
    unsigned short* eagg_bf  = (unsigned short*)carve((size_t)N * 64);
    int*            off      = (int*)carve((size_t)(N + 1) * 4);
    int*            bsum     = (int*)carve(64 * 4);
    float*          sd       = (float*)carve((size_t)N * 4);
    float*          rdeg     = (float*)carve((size_t)N * 4);
    int*            nstart   = (int*)carve((size_t)nblocks * 4);
    unsigned short* Bt       = (unsigned short*)carve(160 * 160 * 2);
    unsigned short* Bte      = (unsigned short*)carve(32 * 32 * 2);
    float*          out      = (float*)d_out;

    const int TB = 256;
    const int NB = (N + 1023) / 1024;
    const int prepn = max(N, 160 * 160 + 32 * 32);
    k_prepw       <<<(prepn + TB - 1) / TB, TB, 0, stream>>>(W_ego, W_peer, W_edge,
                                                             Bt, Bte, deg_i, N);
    k_hist        <<<(E + TB - 1) / TB, TB, 0, stream>>>(row, deg_i, rank, E);
    k_scan_partial<<<NB, TB, 0, stream>>>(deg_i, bsum, N);
    k_scan_final  <<<NB, TB, 0, stream>>>(deg_i, bsum, off, sd, rdeg,
                                          nstart, eagg, sea, N);
    k_scatcvt     <<<(E + TB * 4 - 1) / (TB * 4), TB, 0, stream>>>(ea, row, col, off, rank,
                                                                   easorted, colsort, E);

    k_agg<<<nblocks, 512, 0, stream>>>(easorted, off, nstart, Bte, b_edge,
                                       eagg, sea, eagg_bf, out, N, E);

    const int node_grid = (N + 63) / 64;
    const int fin_grid  = (N * 8 + TB - 1) / TB;
    k_nodecvt<<<node_grid + fin_grid, TB, 0, stream>>>(x, sea, sd, rdeg, Bt,
                                                       b_ego, b_peer, eagg,
                                                       eagg_bf, off, out, N, node_grid);

    const int agg_grid = (N + 3) / 4;
    k_mmagg<<<agg_grid, TB, 0, stream>>>(colsort, off, eagg_bf, out, N);
}

// Round 15
// 179.958 us; speedup vs baseline: 1.0991x; 1.0991x over previous
//
#include <hip/hip_runtime.h>

// ---------------------------------------------------------------------------
// Pipeline (8 launches):
//   k_prepw:     weight bf16 packs + deg zero
//   k_hist:      deg histogram + per-edge rank (1 int atomic/edge)
//   k_scan_partial / k_scan_final: off = scan(deg); sd/rdeg/nstart; zero
//                boundary rows (scan_final self-computes block offsets)
//   k_scatcvt:   ea (streaming, 1 edge/thread) -> bf16 -> easorted[pos]
//                (64B full-line random write, L2-buffered) + colsort (u16)
//   k_agg:       streaming easorted -> MFMA edge GEMV -> LDS -> segmented
//                sums; INTERIOR nodes written in final form (out[:,64:96] +
//                eagg_bf); boundary/empty via fp32 atomics into eagg
//   k_nodecvt:   node blocks: MFMA node GEMM -> out[:,0:64],[128:224];
//                cvt blocks: finalize ONLY boundary/empty nodes
//   k_mmagg:     out[:,96:128] = dinv * gather-sum(eagg_bf[colsort])
// NOTE (r11 lesson): NO nontemporal stores on scattered addresses.
// NOTE (r14 lesson): scatter kernels are latency-bound -> keep 1 edge/thread
// (max waves); 4 edges/thread dropped occupancy 56->19% and cost +27us.
// Math:
//   out[:,  0: 64] = relu(x @ W_ego.T + b_ego)
//   out[:, 64: 96] = eagg[i]  = sum_{e:row=i} relu(ea[e] @ W_edge.T + b_edge)
//   out[:, 96:128] = dinv[i] * sum_{e:row=i} eagg[col[e]]
//   out[:,128:224] = relu( sd * (W_peer @ [x | sea/deg] + b_peer) )
// MFMA fragment maps: A/B k-order cancels (same map both sides); C/D layout
// (HW-verified): col = lane&15, row = (lane>>4)*4 + reg.
// colsort is u16 — requires N <= 65535 (here N = 50000).
// ---------------------------------------------------------------------------

typedef float f32x4 __attribute__((ext_vector_type(4)));
typedef short bf16x8 __attribute__((ext_vector_type(8)));
typedef unsigned short u16x8 __attribute__((ext_vector_type(8)));

#define BP 256   // CSR positions per k_agg block (512 threads, 2 edges/thread)

__device__ __forceinline__ unsigned short f2bf(float f) {
    unsigned u = __float_as_uint(f);
    u += 0x7fffu + ((u >> 16) & 1u);      // RNE
    return (unsigned short)(u >> 16);
}
__device__ __forceinline__ float bf2f(unsigned short u) {
    return __uint_as_float((unsigned)u << 16);
}
__device__ __forceinline__ u16x8 pk8u(float4 lo, float4 hi) {
    u16x8 r;
    r[0]=f2bf(lo.x); r[1]=f2bf(lo.y); r[2]=f2bf(lo.z); r[3]=f2bf(lo.w);
    r[4]=f2bf(hi.x); r[5]=f2bf(hi.y); r[6]=f2bf(hi.z); r[7]=f2bf(hi.w);
    return r;
}
__device__ __forceinline__ bf16x8 mk_frag(ushort4 lo, ushort4 hi) {
    bf16x8 b;
    b[0]=(short)lo.x; b[1]=(short)lo.y; b[2]=(short)lo.z; b[3]=(short)lo.w;
    b[4]=(short)hi.x; b[5]=(short)hi.y; b[6]=(short)hi.z; b[7]=(short)hi.w;
    return b;
}
__device__ __forceinline__ bf16x8 ld_bfrag(const unsigned short* bp) {
    return mk_frag(*reinterpret_cast<const ushort4*>(bp),
                   *reinterpret_cast<const ushort4*>(bp + 16));
}

// weight packs + deg zero (merged)
__global__ __launch_bounds__(256) void k_prepw(const float* __restrict__ W_ego,
                                               const float* __restrict__ W_peer,
                                               const float* __restrict__ W_edge,
                                               unsigned short* __restrict__ Bt,
                                               unsigned short* __restrict__ Bte,
                                               int* __restrict__ deg, int N) {
    int idx = blockIdx.x * blockDim.x + threadIdx.x;
    if (idx < 160 * 160) {
        int n = idx / 160, k = idx % 160;
        float v;
        if (n < 64) v = (k < 128) ? W_ego[n * 128 + k] : 0.f;
        else        v = W_peer[(n - 64) * 160 + k];
        Bt[idx] = f2bf(v);
    } else if (idx < 160 * 160 + 32 * 32) {
        int j = idx - 160 * 160;
        Bte[j] = f2bf(W_edge[j]);
    }
    if (idx < N) deg[idx] = 0;
}

// histogram + per-edge rank within its node
__global__ __launch_bounds__(256) void k_hist(const int* __restrict__ row,
                                              int* __restrict__ deg,
                                              int* __restrict__ rank, int E) {
    int e = blockIdx.x * blockDim.x + threadIdx.x;
    if (e < E) rank[e] = atomicAdd(&deg[row[e]], 1);
}

__global__ __launch_bounds__(256) void k_scan_partial(const int* __restrict__ deg,
                                                      int* __restrict__ bsum, int N) {
    __shared__ int sh[256];
    int base = blockIdx.x * 1024 + threadIdx.x * 4;
    int s = 0;
#pragma unroll
    for (int q = 0; q < 4; ++q) { int i = base + q; if (i < N) s += deg[i]; }
    sh[threadIdx.x] = s;
    __syncthreads();
    for (int off = 128; off > 0; off >>= 1) {
        if (threadIdx.x < off) sh[threadIdx.x] += sh[threadIdx.x + off];
        __syncthreads();
    }
    if (threadIdx.x == 0) bsum[blockIdx.x] = sh[0];
}

// scan-final + per-node prep. Each block derives its own prefix from bsum
// (NB = gridDim.x <= 64), so no separate mid kernel.
__global__ __launch_bounds__(256) void k_scan_final(
    const int* __restrict__ deg, const int* __restrict__ bsum,
    int* __restrict__ off,
    float* __restrict__ sd, float* __restrict__ rdeg, int* __restrict__ nstart,
    float* __restrict__ eagg, float* __restrict__ sea, int N)
{
    __shared__ int sh[256];
    __shared__ int s_boff;
    int t = threadIdx.x;
    int NB = gridDim.x;

    if (t < 64) {                         // one wave computes prefix + total
        int v = (t < NB) ? bsum[t] : 0;
        int p = (t < (int)blockIdx.x) ? v : 0;
#pragma unroll
        for (int m = 1; m < 64; m <<= 1) {
            p += __shfl_xor(p, m);
            v += __shfl_xor(v, m);
        }
        if (t == 0) {
            s_boff = p;
            if (blockIdx.x == 0) off[N] = v;   // total == E
        }
    }
    __syncthreads();

    int base = blockIdx.x * 1024 + t * 4;
    int v[4];
#pragma unroll
    for (int q = 0; q < 4; ++q) v[q] = (base + q < N) ? deg[base + q] : 0;
    int ts = v[0] + v[1] + v[2] + v[3];
    sh[t] = ts;
    __syncthreads();
    int incl = ts;
    for (int d = 1; d < 256; d <<= 1) {
        int val = (t >= d) ? sh[t - d] : 0;
        __syncthreads();
        incl += val;
        sh[t] = incl;
        __syncthreads();
    }
    int running = s_boff + incl - ts;
#pragma unroll
    for (int q = 0; q < 4; ++q) {
        int i = base + q;
        if (i < N) {
            int s = running, e = running + v[q];
            off[i] = s;
            int dg = v[q];
            sd[i]   = dg > 0 ? sqrtf((float)dg) : 0.f;
            rdeg[i] = dg > 0 ? 1.f / (float)dg : 0.f;
            for (int b = (s + BP - 1) / BP; b * BP < e; ++b) nstart[b] = i;
            bool zneed = (dg == 0) || ((s / BP) != ((e - 1) / BP));
            if (zneed) {
                float4 z = {0.f, 0.f, 0.f, 0.f};
                float4* pe = reinterpret_cast<float4*>(eagg + (size_t)i * 32);
                float4* ps = reinterpret_cast<float4*>(sea  + (size_t)i * 32);
#pragma unroll
                for (int q2 = 0; q2 < 8; ++q2) { pe[q2] = z; ps[q2] = z; }
            }
            running = e;
        }
    }
}

// streaming ea read -> bf16 -> full-line (64B) random write at CSR position.
// 1 edge/thread: max wave count == max scatter MLP (r14 lesson).
__global__ __launch_bounds__(256) void k_scatcvt(
    const float* __restrict__ ea, const int* __restrict__ row,
    const int* __restrict__ col, const int* __restrict__ off,
    const int* __restrict__ rank,
    unsigned short* __restrict__ easorted,
    unsigned short* __restrict__ colsort, int E)
{
    int e = blockIdx.x * blockDim.x + threadIdx.x;
    if (e >= E) return;
    int pos = off[row[e]] + rank[e];
    const float4* src = reinterpret_cast<const float4*>(ea + (size_t)e * 32);
    u16x8* dst = reinterpret_cast<u16x8*>(easorted + (size_t)pos * 32);
#pragma unroll
    for (int q = 0; q < 4; ++q)
        dst[q] = pk8u(src[2 * q], src[2 * q + 1]);
    colsort[pos] = (unsigned short)col[e];
}

// Streaming sorted records -> MFMA edge GEMV -> bf16 LDS -> segmented sum.
// Interior nodes finalized here (out[:,64:96] + eagg_bf); boundary/empty via
// fp32 atomics into eagg (zeroed by scan_final), finalized by k_nodecvt.
__global__ __launch_bounds__(512) void k_agg(
    const unsigned short* __restrict__ easorted,
    const int* __restrict__ off, const int* __restrict__ nstart,
    const unsigned short* __restrict__ Bte, const float* __restrict__ b_edge,
    float* __restrict__ eagg, float* __restrict__ sea,
    unsigned short* __restrict__ eagg_bf, float* __restrict__ out, int N, int E)
{
    __shared__ unsigned short hs [BP][36];   // relu(h_e), bf16
    __shared__ unsigned short asr[BP][36];   // raw ea,    bf16
    const int tid  = threadIdx.x;
    const int w    = tid >> 6;
    const int lane = tid & 63;
    const int n16  = lane & 15;
    const int h    = lane >> 4;
    const int P    = blockIdx.x * BP;

    // ---- phase 1: streaming record read + MFMA GEMV (2 edges/thread) ----
    {
        const int tA = w * 32 + n16;                 // block-local CSR pos (tile 0)
        const int p0 = min(P + tA,      E - 1);
        const int p1 = min(P + tA + 16, E - 1);
        const unsigned short* r0 = easorted + (size_t)p0 * 32 + h * 4;
        const unsigned short* r1 = easorted + (size_t)p1 * 32 + h * 4;
        ushort4 lo0 = *reinterpret_cast<const ushort4*>(r0);
        ushort4 hi0 = *reinterpret_cast<const ushort4*>(r0 + 16);
        ushort4 lo1 = *reinterpret_cast<const ushort4*>(r1);
        ushort4 hi1 = *reinterpret_cast<const ushort4*>(r1 + 16);

        *reinterpret_cast<ushort4*>(&asr[tA][h * 4])           = lo0;
        *reinterpret_cast<ushort4*>(&asr[tA][16 + h * 4])      = hi0;
        *reinterpret_cast<ushort4*>(&asr[tA + 16][h * 4])      = lo1;
        *reinterpret_cast<ushort4*>(&asr[tA + 16][16 + h * 4]) = hi1;

        bf16x8 a0 = mk_frag(lo0, hi0);
        bf16x8 a1 = mk_frag(lo1, hi1);
        bf16x8 b0 = ld_bfrag(Bte + (size_t)n16 * 32 + h * 4);
        bf16x8 b1 = ld_bfrag(Bte + (size_t)(16 + n16) * 32 + h * 4);
        f32x4 d00 = {0.f,0.f,0.f,0.f}, d01 = {0.f,0.f,0.f,0.f};
        f32x4 d10 = {0.f,0.f,0.f,0.f}, d11 = {0.f,0.f,0.f,0.f};
        d00 = __builtin_amdgcn_mfma_f32_16x16x32_bf16(a0, b0, d00, 0, 0, 0);
        d01 = __builtin_amdgcn_mfma_f32_16x16x32_bf16(a0, b1, d01, 0, 0, 0);
        d10 = __builtin_amdgcn_mfma_f32_16x16x32_bf16(a1, b0, d10, 0, 0, 0);
        d11 = __builtin_amdgcn_mfma_f32_16x16x32_bf16(a1, b1, d11, 0, 0, 0);

        const int tr0 = w * 32 + h * 4;              // D row base = edge
        float be0 = b_edge[n16], be1 = b_edge[16 + n16];
#pragma unroll
        for (int r = 0; r < 4; ++r) {
            hs[tr0 + r][n16]           = f2bf(fmaxf(d00[r] + be0, 0.f));
            hs[tr0 + r][16 + n16]      = f2bf(fmaxf(d01[r] + be1, 0.f));
            hs[tr0 + 16 + r][n16]      = f2bf(fmaxf(d10[r] + be0, 0.f));
            hs[tr0 + 16 + r][16 + n16] = f2bf(fmaxf(d11[r] + be1, 0.f));
        }
    }
    __syncthreads();

    // ---- phase 2: segmented sums from LDS (nstart precomputed) ----
    const int c = lane & 7, sub = lane >> 3;
    const int node0 = nstart[blockIdx.x];

    for (int n = node0 + w; n < N; n += 8) {
        int s0 = off[n];
        if (s0 >= P + BP) break;                     // off monotone -> done
        int e0 = off[n + 1];
        int s = max(s0, P) - P, eEnd = min(e0, P + BP) - P;
        float4 hv = {0.f,0.f,0.f,0.f}, av = {0.f,0.f,0.f,0.f};
        for (int t = s + sub; t < eEnd; t += 8) {
            ushort4 uh = *reinterpret_cast<const ushort4*>(&hs [t][c * 4]);
            ushort4 ua = *reinterpret_cast<const ushort4*>(&asr[t][c * 4]);
            hv.x += bf2f(uh.x); hv.y += bf2f(uh.y); hv.z += bf2f(uh.z); hv.w += bf2f(uh.w);
            av.x += bf2f(ua.x); av.y += bf2f(ua.y); av.z += bf2f(ua.z); av.w += bf2f(ua.w);
        }
#pragma unroll
        for (int m = 8; m < 64; m <<= 1) {
            hv.x += __shfl_xor(hv.x, m); hv.y += __shfl_xor(hv.y, m);
            hv.z += __shfl_xor(hv.z, m); hv.w += __shfl_xor(hv.w, m);
            av.x += __shfl_xor(av.x, m); av.y += __shfl_xor(av.y, m);
            av.z += __shfl_xor(av.z, m); av.w += __shfl_xor(av.w, m);
        }
        if (lane < 8) {
            bool interior = (s0 >= P) && (e0 <= P + BP);
            float* ps = sea + (size_t)n * 32 + c * 4;
            if (interior) {
                // finalize directly: out[:,64:96] fp32 + eagg_bf bf16 + sea
                *reinterpret_cast<float4*>(out + (size_t)n * 224 + 64 + c * 4) = hv;
                ushort4 ub = {f2bf(hv.x), f2bf(hv.y), f2bf(hv.z), f2bf(hv.w)};
                *reinterpret_cast<ushort4*>(eagg_bf + (size_t)n * 32 + c * 4) = ub;
                *reinterpret_cast<float4*>(ps) = av;
            } else {
                float* pe = eagg + (size_t)n * 32 + c * 4;
                atomicAdd(pe+0,hv.x); atomicAdd(pe+1,hv.y);
                atomicAdd(pe+2,hv.z); atomicAdd(pe+3,hv.w);
                atomicAdd(ps+0,av.x); atomicAdd(ps+1,av.y);
                atomicAdd(ps+2,av.z); atomicAdd(ps+3,av.w);
            }
        }
    }
}

// Merged: blocks [0, node_grid) = MFMA node GEMM; blocks after = finalize
// boundary/empty nodes only (eagg fp32 -> eagg_bf + out[:,64:96]).
__global__ __launch_bounds__(256) void k_nodecvt(
    const float* __restrict__ x, const float* __restrict__ sea,
    const float* __restrict__ sd, const float* __restrict__ rdeg,
    const unsigned short* __restrict__ Bt,
    const float* __restrict__ b_ego, const float* __restrict__ b_peer,
    const float* __restrict__ eagg, unsigned short* __restrict__ eagg_bf,
    const int* __restrict__ off,
    float* __restrict__ out, int N, int node_grid)
{
    if ((int)blockIdx.x >= node_grid) {
        // ---- finalize boundary/empty nodes ----
        int idx = (blockIdx.x - node_grid) * 256 + threadIdx.x;
        if (idx >= N * 8) return;
        int node = idx >> 3, c = idx & 7;
        int s = off[node], e = off[node + 1];
        int dg = e - s;
        bool zneed = (dg == 0) || ((s / BP) != ((e - 1) / BP));
        if (!zneed) return;
        float4 v = reinterpret_cast<const float4*>(eagg + (size_t)node * 32)[c];
        ushort4 u = {f2bf(v.x), f2bf(v.y), f2bf(v.z), f2bf(v.w)};
        *reinterpret_cast<ushort4*>(eagg_bf + (size_t)node * 32 + c * 4) = u;
        reinterpret_cast<float4*>(out + (size_t)node * 224 + 64)[c] = v;
        return;
    }
    // ---- node GEMM part: block = 4 waves, wave = 16 nodes x 160 outputs ----
    const int lane = threadIdx.x & 63;
    const int wv   = threadIdx.x >> 6;
    const int wm   = blockIdx.x * 64 + wv * 16;
    const int n16  = lane & 15;
    const int h    = lane >> 4;

    const int m_l = min(wm + n16, N - 1);

    f32x4 acc[10];
#pragma unroll
    for (int f = 0; f < 10; ++f) acc[f] = (f32x4){0.f,0.f,0.f,0.f};

#pragma unroll
    for (int kc = 0; kc < 5; ++kc) {
        bf16x8 bfr[10];
#pragma unroll
        for (int f = 0; f < 10; ++f)
            bfr[f] = ld_bfrag(Bt + (size_t)(f * 16 + n16) * 160 + kc * 32 + h * 4);
        float4 lo, hi;
        if (kc < 4) {
            const float* ap = x + (size_t)m_l * 128 + kc * 32 + h * 4;
            lo = *reinterpret_cast<const float4*>(ap);
            hi = *reinterpret_cast<const float4*>(ap + 16);
        } else {
            float r = rdeg[m_l];
            const float* ap = sea + (size_t)m_l * 32 + h * 4;
            lo = *reinterpret_cast<const float4*>(ap);
            hi = *reinterpret_cast<const float4*>(ap + 16);
            lo.x*=r; lo.y*=r; lo.z*=r; lo.w*=r;
            hi.x*=r; hi.y*=r; hi.z*=r; hi.w*=r;
        }
        u16x8 au = pk8u(lo, hi);
        bf16x8 a;
#pragma unroll
        for (int q = 0; q < 8; ++q) a[q] = (short)au[q];
#pragma unroll
        for (int f = 0; f < 10; ++f)
            acc[f] = __builtin_amdgcn_mfma_f32_16x16x32_bf16(a, bfr[f], acc[f], 0, 0, 0);
    }

    const int r4 = h * 4;
    float sdv[4];
#pragma unroll
    for (int r = 0; r < 4; ++r) {
        int node = wm + r4 + r;
        sdv[r] = (node < N) ? sd[node] : 0.f;
    }
#pragma unroll
    for (int f = 0; f < 10; ++f) {
        int c = f * 16 + n16;
        float be = (c < 64)  ? b_ego[c] : 0.f;
        float bp = (c >= 64) ? b_peer[c - 64] : 0.f;
#pragma unroll
        for (int r = 0; r < 4; ++r) {
            int node = wm + r4 + r;
            if (node >= N) continue;
            float v = acc[f][r];
            if (c < 64)
                out[(size_t)node * 224 + c] = fmaxf(v + be, 0.f);
            else
                out[(size_t)node * 224 + 64 + c] = fmaxf(sdv[r] * (v + bp), 0.f);
        }
    }
}

// out[:,96:128] = dinv * gather-sum(eagg_bf[colsort])  (64B L2-hit gathers)
__global__ __launch_bounds__(256) void k_mmagg(
    const unsigned short* __restrict__ colsort, const int* __restrict__ off,
    const unsigned short* __restrict__ eagg_bf, float* __restrict__ out, int N)
{
    int wid  = (blockIdx.x * blockDim.x + threadIdx.x) >> 6;
    int lane = threadIdx.x & 63;
    if (wid >= N) return;
    int s = off[wid], e = off[wid + 1];
    int c   = lane & 7;
    int sub = lane >> 3;
    float4 acc = {0.f, 0.f, 0.f, 0.f};
    float4 acc2 = {0.f, 0.f, 0.f, 0.f};
    for (int t0 = s; t0 < e; t0 += 16) {
        int t1 = t0 + sub, t2 = t0 + 8 + sub;
        if (t1 < e) {
            ushort4 u = *reinterpret_cast<const ushort4*>(
                eagg_bf + (size_t)colsort[t1] * 32 + c * 4);
            acc.x += bf2f(u.x); acc.y += bf2f(u.y);
            acc.z += bf2f(u.z); acc.w += bf2f(u.w);
        }
        if (t2 < e) {
            ushort4 u = *reinterpret_cast<const ushort4*>(
                eagg_bf + (size_t)colsort[t2] * 32 + c * 4);
            acc2.x += bf2f(u.x); acc2.y += bf2f(u.y);
            acc2.z += bf2f(u.z); acc2.w += bf2f(u.w);
        }
    }
    acc.x += acc2.x; acc.y += acc2.y; acc.z += acc2.z; acc.w += acc2.w;
#pragma unroll
    for (int m = 8; m < 64; m <<= 1) {
        acc.x += __shfl_xor(acc.x, m);
        acc.y += __shfl_xor(acc.y, m);
        acc.z += __shfl_xor(acc.z, m);
        acc.w += __shfl_xor(acc.w, m);
    }
    int dg = e - s;
    float dinv = dg > 0 ? rsqrtf((float)dg) : 0.f;
    if (lane < 8) {
        float4 o4 = {acc.x * dinv, acc.y * dinv, acc.z * dinv, acc.w * dinv};
        reinterpret_cast<float4*>(out + (size_t)wid * 224 + 96)[c] = o4;
    }
}

extern "C" void kernel_launch(void* const* d_in, const int* in_sizes, int n_in,
                              void* d_out, int out_size, void* d_ws, size_t ws_size,
                              hipStream_t stream)
{
    const float* x      = (const float*)d_in[0];
    const float* ea     = (const float*)d_in[1];
    const float* W_peer = (const float*)d_in[2];
    const float* b_peer = (const float*)d_in[3];
    const float* W_ego  = (const float*)d_in[4];
    const float* b_ego  = (const float*)d_in[5];
    const float* W_edge = (const float*)d_in[6];
    const float* b_edge = (const float*)d_in[7];
    const int*   ei     = (const int*)d_in[8];

    const int N = in_sizes[0] / 128;
    const int E = in_sizes[8] / 2;
    const int* col = ei;
    const int* row = ei + E;
    const int nblocks = (E + BP - 1) / BP;

    // 16B-aligned workspace carve-out
    char* wp = (char*)d_ws;
    auto carve = [&](size_t bytes) { char* r = wp; wp += (bytes + 15) & ~(size_t)15; return r; };
    int*            rank     = (int*)carve((size_t)E * 4);
    unsigned short* easorted = (unsigned short*)carve((size_t)E * 64);
    unsigned short* colsort  = (unsigned short*)carve((size_t)E * 2);
    int*            deg_i    = (int*)carve((size_t)N * 4);
    float*          eagg     = (float*)carve((size_t)N * 128);
    float*          sea      = (float*)carve((size_t)N * 128);
    unsigned short* eagg_bf  = (unsigned short*)carve((size_t)N * 64);
    int*            off      = (int*)carve((size_t)(N + 1) * 4);
    int*            bsum     = (int*)carve(64 * 4);
    float*          sd       = (float*)carve((size_t)N * 4);
    float*          rdeg     = (float*)carve((size_t)N * 4);
    int*            nstart   = (int*)carve((size_t)nblocks * 4);
    unsigned short* Bt       = (unsigned short*)carve(160 * 160 * 2);
    unsigned short* Bte      = (unsigned short*)carve(32 * 32 * 2);
    float*          out      = (float*)d_out;

    const int TB = 256;
    const int NB = (N + 1023) / 1024;
    const int prepn = max(N, 160 * 160 + 32 * 32);
    k_prepw       <<<(prepn + TB - 1) / TB, TB, 0, stream>>>(W_ego, W_peer, W_edge,
                                                             Bt, Bte, deg_i, N);
    k_hist        <<<(E + TB - 1) / TB, TB, 0, stream>>>(row, deg_i, rank, E);
    k_scan_partial<<<NB, TB, 0, stream>>>(deg_i, bsum, N);
    k_scan_final  <<<NB, TB, 0, stream>>>(deg_i, bsum, off, sd, rdeg,
                                          nstart, eagg, sea, N);
    k_scatcvt     <<<(E + TB - 1) / TB, TB, 0, stream>>>(ea, row, col, off, rank,
                                                         easorted, colsort, E);

    k_agg<<<nblocks, 512, 0, stream>>>(easorted, off, nstart, Bte, b_edge,
                                       eagg, sea, eagg_bf, out, N, E);

    const int node_grid = (N + 63) / 64;
    const int fin_grid  = (N * 8 + TB - 1) / TB;
    k_nodecvt<<<node_grid + fin_grid, TB, 0, stream>>>(x, sea, sd, rdeg, Bt,
                                                       b_ego, b_peer, eagg,
                                                       eagg_bf, off, out, N, node_grid);

    const int agg_grid = (N + 3) / 4;
    k_mmagg<<<agg_grid, TB, 0, stream>>>(colsort, off, eagg_bf, out, N);
}